// Round 3
// baseline (953.654 us; speedup 1.0000x reference)
//
#include <hip/hip_runtime.h>
#include <stdint.h>

typedef unsigned short ushort_t;
typedef __bf16 bf16x8 __attribute__((ext_vector_type(8)));
typedef float f32x4 __attribute__((ext_vector_type(4)));
typedef unsigned short us8 __attribute__((ext_vector_type(8)));
typedef unsigned short us4 __attribute__((ext_vector_type(4)));

#define BB 8
#define TT 2048
#define CC 1024
#define NEG_INF_F (-4294967295.0f)

__device__ __forceinline__ float bf2f(ushort_t u) {
    union { unsigned int i; float f; } v; v.i = ((unsigned int)u) << 16; return v.f;
}
__device__ __forceinline__ ushort_t f2bf(float f) {   // RNE
    union { float f; unsigned int i; } v; v.f = f;
    unsigned int r = (v.i + 0x7fffu + ((v.i >> 16) & 1u)) >> 16;
    return (ushort_t)r;
}
// pack two f32 -> two bf16 (round-half-up): low half = a, high half = b
__device__ __forceinline__ unsigned int pkbf(float a, float b) {
    union { float f; unsigned int i; } ua, ub;
    ua.f = a; ub.f = b;
    return __builtin_amdgcn_perm(ua.i + 0x8000u, ub.i + 0x8000u, 0x03020706u);
}

// ---------------- generic MFMA GEMM:  C = epi(alpha * A @ B^T) ----------------
// A: [M,K] row-major f32 (aF32=1) or bf16 (aF32=0); Bm: [N,K] row-major bf16.
// C row-major, f32 (outF32=1) or bf16. Batched via blockIdx.z (strides in elems;
// sCbBytes in bytes). epi: 0=none 1=relu 2=relu*aux[col] 3=+aux[col]
// 4=relu(+aux[col]) 5=+aux[z,row,col]. aux is f32.
#define TM 128
#define TN 128
#define BK 32
#define LDSS 40   // 32 + 8 pad elems (80B row stride -> 2-way bank aliasing, free per m136)

__global__ __launch_bounds__(256) void gemm_bt(
    const void* __restrict__ Av, long sAb, int lda, int aF32,
    const ushort_t* __restrict__ Bm, long sBb, int ldb,
    void* __restrict__ Cm, long sCbBytes, int ldc, int outF32,
    int K, float alpha, int epi,
    const float* __restrict__ aux, long sAuxb, int ldaux)
{
    __shared__ ushort_t aT[TM * LDSS];
    __shared__ ushort_t bT[TN * LDSS];
    const int z = blockIdx.z;
    Bm += (long)z * sBb;
    char* Cb = (char*)Cm + (long)z * sCbBytes;
    const int m0 = blockIdx.y * TM, n0 = blockIdx.x * TN;
    const int tid = threadIdx.x;
    const int w = tid >> 6, lane = tid & 63;
    const int wm = w >> 1, wn = w & 1;
    const int l15 = lane & 15, q = lane >> 4;

    f32x4 acc[4][4] = {};

    const int r0 = tid >> 2;             // 0..63
    const int kc0 = (tid & 3) * 8;       // 0,8,16,24

    const ushort_t* Ab = (const ushort_t*)Av + (long)z * sAb;
    const float*    Af = (const float*)Av + (long)z * sAb;

    for (int k0 = 0; k0 < K; k0 += BK) {
        uint4 va0, va1;
        if (aF32) {
            const float* p0 = Af + (long)(m0 + r0) * lda + k0 + kc0;
            const float* p1 = p0 + (long)64 * lda;
            float4 x0 = *(const float4*)p0, x1 = *(const float4*)(p0 + 4);
            float4 y0 = *(const float4*)p1, y1 = *(const float4*)(p1 + 4);
            va0 = make_uint4(pkbf(x0.x, x0.y), pkbf(x0.z, x0.w), pkbf(x1.x, x1.y), pkbf(x1.z, x1.w));
            va1 = make_uint4(pkbf(y0.x, y0.y), pkbf(y0.z, y0.w), pkbf(y1.x, y1.y), pkbf(y1.z, y1.w));
        } else {
            va0 = *(const uint4*)(Ab + (long)(m0 + r0) * lda + k0 + kc0);
            va1 = *(const uint4*)(Ab + (long)(m0 + r0 + 64) * lda + k0 + kc0);
        }
        uint4 vb0 = *(const uint4*)(Bm + (long)(n0 + r0) * ldb + k0 + kc0);
        uint4 vb1 = *(const uint4*)(Bm + (long)(n0 + r0 + 64) * ldb + k0 + kc0);
        __syncthreads();   // previous iter's frag reads done before overwrite
        *(uint4*)(aT + r0 * LDSS + kc0) = va0;
        *(uint4*)(aT + (r0 + 64) * LDSS + kc0) = va1;
        *(uint4*)(bT + r0 * LDSS + kc0) = vb0;
        *(uint4*)(bT + (r0 + 64) * LDSS + kc0) = vb1;
        __syncthreads();
        bf16x8 af[4], bfr[4];
        #pragma unroll
        for (int i = 0; i < 4; i++)
            af[i] = *(bf16x8*)(aT + (wm * 64 + i * 16 + l15) * LDSS + q * 8);
        #pragma unroll
        for (int j = 0; j < 4; j++)
            bfr[j] = *(bf16x8*)(bT + (wn * 64 + j * 16 + l15) * LDSS + q * 8);
        #pragma unroll
        for (int i = 0; i < 4; i++)
            #pragma unroll
            for (int j = 0; j < 4; j++)
                acc[i][j] = __builtin_amdgcn_mfma_f32_16x16x32_bf16(af[i], bfr[j], acc[i][j], 0, 0, 0);
    }

    // epilogue: D lane mapping col = lane&15, row = (lane>>4)*4 + r  (m89-verified)
    #pragma unroll
    for (int i = 0; i < 4; i++) {
        #pragma unroll
        for (int r = 0; r < 4; r++) {
            const int row = m0 + wm * 64 + i * 16 + q * 4 + r;
            #pragma unroll
            for (int j = 0; j < 4; j++) {
                const int col = n0 + wn * 64 + j * 16 + l15;
                float v = acc[i][j][r] * alpha;
                if (epi == 1) v = fmaxf(v, 0.0f);
                else if (epi == 2) v = fmaxf(v, 0.0f) * aux[col];
                else if (epi == 3) v = v + aux[col];
                else if (epi == 4) v = fmaxf(v + aux[col], 0.0f);
                else if (epi == 5) v = v + aux[(long)z * sAuxb + (long)row * ldaux + col];
                if (outF32) ((float*)Cb)[(long)row * ldc + col] = v;
                else        ((ushort_t*)Cb)[(long)row * ldc + col] = f2bf(v);
            }
        }
    }
}

// ---------------- cast-transpose: out[z][c][r] = bf16(in[z][r][c]), in f32 ----------------
__global__ __launch_bounds__(256) void transpose_f32_bf16(
    const float* __restrict__ in, ushort_t* __restrict__ out,
    int R, int Cn, long sIn, long sOut)
{
    __shared__ ushort_t tile[32][33];
    in += (long)blockIdx.z * sIn;
    out += (long)blockIdx.z * sOut;
    const int c0 = blockIdx.x * 32, r0 = blockIdx.y * 32;
    const int tx = threadIdx.x & 31, ty = threadIdx.x >> 5;   // ty 0..7
    #pragma unroll
    for (int i = 0; i < 4; i++)
        tile[ty + i * 8][tx] = f2bf(in[(long)(r0 + ty + i * 8) * Cn + c0 + tx]);
    __syncthreads();
    #pragma unroll
    for (int i = 0; i < 4; i++)
        out[(long)(c0 + ty + i * 8) * R + r0 + tx] = tile[tx][ty + i * 8];
}

// ---------------- row softmax over S (bf16, in place), f32 masks applied ----------------
__global__ __launch_bounds__(256) void softmax_k(
    ushort_t* __restrict__ S, const float* __restrict__ km, const float* __restrict__ qm)
{
    const long row = blockIdx.x;        // 0..B*T-1 ; b = row>>11
    const int b = (int)(row >> 11);
    ushort_t* Sr = S + row * TT;
    const int tid = threadIdx.x;
    us8 sv = *(us8*)(Sr + tid * 8);
    const float* kmr = km + (long)b * TT + tid * 8;
    float4 k0 = *(const float4*)kmr, k1 = *(const float4*)(kmr + 4);
    float kmv[8] = {k0.x, k0.y, k0.z, k0.w, k1.x, k1.y, k1.z, k1.w};
    float v[8];
    #pragma unroll
    for (int j = 0; j < 8; j++)
        v[j] = (kmv[j] == 0.0f) ? NEG_INF_F : bf2f(sv[j]);
    float mx = v[0];
    #pragma unroll
    for (int j = 1; j < 8; j++) mx = fmaxf(mx, v[j]);
    #pragma unroll
    for (int off = 32; off > 0; off >>= 1) mx = fmaxf(mx, __shfl_xor(mx, off));
    __shared__ float red[8];
    if ((tid & 63) == 0) red[tid >> 6] = mx;
    __syncthreads();
    mx = fmaxf(fmaxf(red[0], red[1]), fmaxf(red[2], red[3]));
    float e[8], s = 0.0f;
    #pragma unroll
    for (int j = 0; j < 8; j++) { e[j] = __expf(v[j] - mx); s += e[j]; }
    #pragma unroll
    for (int off = 32; off > 0; off >>= 1) s += __shfl_xor(s, off);
    if ((tid & 63) == 0) red[4 + (tid >> 6)] = s;
    __syncthreads();
    s = red[4] + red[5] + red[6] + red[7];
    const float scale = qm[row] / s;
    us8 o;
    #pragma unroll
    for (int j = 0; j < 8; j++) o[j] = f2bf(e[j] * scale);
    *(us8*)(Sr + tid * 8) = o;   // same addresses this thread read: no hazard
}

// ---------------- LayerNorm rows of bf16 -> bf16 (f32 gamma/beta) ----------------
__global__ __launch_bounds__(256) void ln_k(
    const ushort_t* __restrict__ olin, ushort_t* __restrict__ outp,
    const float* __restrict__ gamma, const float* __restrict__ beta)
{
    const long row = blockIdx.x;
    const ushort_t* xr = olin + row * CC;
    const int tid = threadIdx.x;
    us4 xq = *(const us4*)(xr + tid * 4);
    float xs[4] = {bf2f(xq[0]), bf2f(xq[1]), bf2f(xq[2]), bf2f(xq[3])};
    float s = xs[0] + xs[1] + xs[2] + xs[3];
    float ss = xs[0]*xs[0] + xs[1]*xs[1] + xs[2]*xs[2] + xs[3]*xs[3];
    #pragma unroll
    for (int off = 32; off > 0; off >>= 1) { s += __shfl_xor(s, off); ss += __shfl_xor(ss, off); }
    __shared__ float red[8];
    if ((tid & 63) == 0) { red[tid >> 6] = s; red[4 + (tid >> 6)] = ss; }
    __syncthreads();
    s = red[0] + red[1] + red[2] + red[3];
    ss = red[4] + red[5] + red[6] + red[7];
    const float mu = s * (1.0f / CC);
    const float var = ss * (1.0f / CC) - mu * mu;
    const float rstd = rsqrtf(var + 1e-6f);
    float4 gv = *(const float4*)(gamma + tid * 4);
    float4 bv = *(const float4*)(beta + tid * 4);
    float gs[4] = {gv.x, gv.y, gv.z, gv.w}, bs[4] = {bv.x, bv.y, bv.z, bv.w};
    us4 o;
    #pragma unroll
    for (int j = 0; j < 4; j++)
        o[j] = f2bf((xs[j] - mu) * rstd * gs[j] + bs[j]);
    *(us4*)(outp + row * CC + tid * 4) = o;
}

extern "C" void kernel_launch(void* const* d_in, const int* in_sizes, int n_in,
                              void* d_out, int out_size, void* d_ws, size_t ws_size,
                              hipStream_t stream)
{
    // ALL inputs/outputs are FLOAT32 (round-2 diagnosis: byte-copy of 32MiB of
    // queries reproduced exactly half of output0; threshold = 0.02*max|ref|).
    const float* queries     = (const float*)d_in[0];
    const float* keys        = (const float*)d_in[1];
    const float* key_masks   = (const float*)d_in[2];
    const float* query_masks = (const float*)d_in[3];
    const float* u           = (const float*)d_in[4];
    const float* dd          = (const float*)d_in[5];
    const float* W1          = (const float*)d_in[6];
    const float* b1          = (const float*)d_in[7];
    const float* W2          = (const float*)d_in[8];
    const float* b2          = (const float*)d_in[9];
    const float* g1          = (const float*)d_in[10];
    const float* be1         = (const float*)d_in[11];

    // ws layout, lifetime-packed into EXACTLY 128 MiB (= out_nbytes, the most
    // conservative plausible ws_size). All internal staging is bf16.
    //   [0,32):   f1              -> after S-gemm:  keysT      -> after AV: W1T@0, W2T@2
    //   [32,64):  f2              -> after S-gemm:  olin (bf16)
    //   [64,128): uT@64 (2MiB, pre-S) then S/P     -> after AV: lnb@64, hb@96
    char* ws = (char*)d_ws;
    const long MiB = 1 << 20;
    ushort_t* f1    = (ushort_t*)(ws + 0 * MiB);
    ushort_t* f2    = (ushort_t*)(ws + 32 * MiB);
    ushort_t* S     = (ushort_t*)(ws + 64 * MiB);
    ushort_t* uT    = (ushort_t*)(ws + 64 * MiB);   // dead once S-gemm writes
    ushort_t* keysT = (ushort_t*)(ws + 0 * MiB);    // f1 dead after S-gemm
    ushort_t* olin  = (ushort_t*)(ws + 32 * MiB);   // f2 dead after S-gemm
    ushort_t* W1T   = (ushort_t*)(ws + 0 * MiB);    // keysT dead after AV
    ushort_t* W2T   = (ushort_t*)(ws + 2 * MiB);
    ushort_t* lnb   = (ushort_t*)(ws + 64 * MiB);   // S dead after AV
    ushort_t* hb    = (ushort_t*)(ws + 96 * MiB);
    (void)in_sizes; (void)n_in; (void)out_size; (void)ws_size;

    // output 0: queries passthrough (f32, 64 MiB)
    hipMemcpyAsync(d_out, d_in[0], (size_t)BB * TT * CC * sizeof(float),
                   hipMemcpyDeviceToDevice, stream);

    // uT[d][c] = bf16(u[c][d])
    transpose_f32_bf16<<<dim3(CC / 32, CC / 32, 1), 256, 0, stream>>>(u, uT, CC, CC, 0, 0);

    // f1 = relu(Q@u) * d_diag[col]   (A = queries f32, converted in staging)
    gemm_bt<<<dim3(CC / TN, (BB * TT) / TM, 1), 256, 0, stream>>>(
        queries, 0, CC, 1, uT, 0, CC, f1, 0, CC, 0, CC, 1.0f, 2, dd, 0, 0);
    // f2 = relu(K@u)
    gemm_bt<<<dim3(CC / TN, (BB * TT) / TM, 1), 256, 0, stream>>>(
        keys, 0, CC, 1, uT, 0, CC, f2, 0, CC, 0, CC, 1.0f, 1, nullptr, 0, 0);
    // S[b] = (f1[b] @ f2[b]^T) / 32   (bf16 out; scores O(5e-3), bf16-safe)
    gemm_bt<<<dim3(TT / TN, TT / TM, BB), 256, 0, stream>>>(
        f1, (long)TT * CC, CC, 0, f2, (long)TT * CC, CC,
        S, (long)TT * TT * 2, TT, 0, CC, 1.0f / 32.0f, 0, nullptr, 0, 0);
    // softmax rows (key mask -> NEG_INF, multiply by query mask), in place -> P
    softmax_k<<<BB * TT, 256, 0, stream>>>(S, key_masks, query_masks);
    // keysT[b][c][t] = bf16(keys[b][t][c])   (into dead f1 region)
    transpose_f32_bf16<<<dim3(CC / 32, TT / 32, BB), 256, 0, stream>>>(
        keys, keysT, TT, CC, (long)TT * CC, (long)CC * TT);
    // olin[b] = P[b] @ keys[b] + queries[b]   (bf16 out into dead f2 region;
    // queries residual added in f32 via epi 5)
    gemm_bt<<<dim3(CC / TN, TT / TM, BB), 256, 0, stream>>>(
        S, (long)TT * TT, TT, 0, keysT, (long)CC * TT, TT,
        olin, (long)TT * CC * 2, CC, 0, TT, 1.0f, 5, queries, (long)TT * CC, CC);
    // W1T/W2T (into dead keysT region)
    transpose_f32_bf16<<<dim3(CC / 32, CC / 32, 1), 256, 0, stream>>>(W1, W1T, CC, CC, 0, 0);
    transpose_f32_bf16<<<dim3(CC / 32, CC / 32, 1), 256, 0, stream>>>(W2, W2T, CC, CC, 0, 0);
    // LayerNorm -> lnb (into dead S region)
    ln_k<<<BB * TT, 256, 0, stream>>>(olin, lnb, g1, be1);
    // h = relu(ln @ W1 + b1)
    gemm_bt<<<dim3(CC / TN, (BB * TT) / TM, 1), 256, 0, stream>>>(
        lnb, 0, CC, 0, W1T, 0, CC, hb, 0, CC, 0, CC, 1.0f, 4, b1, 0, 0);
    // out2 = h @ W2 + b2 -> d_out second half, f32
    gemm_bt<<<dim3(CC / TN, (BB * TT) / TM, 1), 256, 0, stream>>>(
        hb, 0, CC, 0, W2T, 0, CC, (float*)d_out + (long)BB * TT * CC, 0, CC, 1,
        CC, 1.0f, 3, b2, 0, 0);
}